// Round 10
// baseline (145.075 us; speedup 1.0000x reference)
//
#include <hip/hip_runtime.h>
#include <hip/hip_bf16.h>
#include <hip/hip_fp16.h>

#define B_  64
#define C_  32
#define N_  1152
#define DI_ 8
#define DC_ 16
#define STH 512              // 8 waves

// main-path geometry
#define HCH 2                // n's per staged chunk (wlds 32KB)
#define HSLOT 192            // chunk-slots; slot handles chunks slot, +192, +384
#define NU  192              // route units of 6 n, one WAVE each (no block reduce)

// fallback geometry (R5 path)
#define FCH 3
#define FSLOT 128

static __device__ __forceinline__ unsigned pkh(float a, float b) {
    __half2 t = __float22half2_rn(make_float2(a, b));
    return *reinterpret_cast<unsigned*>(&t);
}
static __device__ __forceinline__ float2 uph(unsigned u) {
    __half2 h; *reinterpret_cast<unsigned*>(&h) = u;
    return __half22float2(h);
}

// ---------------- caps_hat: hat = W@x once, fp16 out, + t=0 partials -------
// R16 (kept): allocator targets 64 VGPR whenever LDS=32KB and spills to get
// there; so fit 64 for real: bq=1 (wave owns ONE b; 8 b/block, grid 1536 =
// 8bg x 192 slots). Peak live ~46 VGPR, 4+ blocks/CU hide staging latency.
// XCD banding: bid&7 = xcd owns slots [24*xcd, 24*xcd+24) -- all 8 bg-blocks
// of a slot share one XCD so W is fetched once per L2.
__global__ __launch_bounds__(STH, 2) void caps_hat(
    const float* __restrict__ X, const float* __restrict__ W,
    uint4* __restrict__ hatg, __half2* __restrict__ p1)
{
    __shared__ float wlds[HCH * 64 * 64];    // [nl][f=2c+h][phys quad q^(c&7)]

    const int xcd  = blockIdx.x & 7;
    const int k    = blockIdx.x >> 3;        // 0..191
    const int bg   = k & 7;                  // 0..7 (8 b's each)
    const int slot = 24 * xcd + (k >> 3);    // 0..191, contiguous band per XCD

    const int tid  = threadIdx.x;
    const int lane = tid & 63;
    const int c    = lane & 31;
    const int h    = lane >> 5;
    const int le   = 2 * c + h;
    const int sw   = c & 7;
    const int wu   = __builtin_amdgcn_readfirstlane(tid) >> 6;  // uniform wave id
    const int b    = bg * 8 + wu;            // this wave's batch index

    float acc[8];
#pragma unroll
    for (int r = 0; r < 8; r++) acc[r] = 0.f;

    for (int cc = 0; cc < 3; cc++) {
        if (cc) __syncthreads();
        const int n0 = (slot + cc * HSLOT) * HCH;

#pragma unroll
        for (int G = tid; G < HCH * 1024; G += STH) {   // 4 iters
            const int nl = G >> 10, f = (G >> 4) & 63, q = G & 15;
            const int wc = f >> 1, wh = f & 1;
            const float4 v = *(const float4*)(W + (size_t)(wc * N_ + n0 + nl) * 128 + wh * 64 + q * 4);
            *(float4*)(wlds + (nl * 64 + f) * 64 + (q ^ (wc & 7)) * 4) = v;
        }
        __syncthreads();

#pragma unroll
        for (int nl = 0; nl < HCH; nl++) {
            const float* xp = X + ((size_t)b * N_ + n0 + nl) * DI_;
            const float4 xa = *(const float4*)xp;
            const float4 xb = *(const float4*)(xp + 4);
            uint4 hq;
            const float* frag = wlds + (nl * 64 + le) * 64;
#pragma unroll
            for (int rp = 0; rp < 4; rp++) {
                const int r0 = 2 * rp, r1 = r0 + 1;
                const int pa0 = ((2 * r0) ^ sw) * 4;
                const int pb0 = pa0 ^ 4;
                const int pa1 = ((2 * r1) ^ sw) * 4;
                const int pb1 = pa1 ^ 4;
                const float4 wa0 = *(const float4*)(frag + pa0);
                const float4 wb0 = *(const float4*)(frag + pb0);
                const float4 wa1 = *(const float4*)(frag + pa1);
                const float4 wb1 = *(const float4*)(frag + pb1);
                const float hv0 = wa0.x*xa.x + wa0.y*xa.y + wa0.z*xa.z + wa0.w*xa.w
                                + wb0.x*xb.x + wb0.y*xb.y + wb0.z*xb.z + wb0.w*xb.w;
                const float hv1 = wa1.x*xa.x + wa1.y*xa.y + wa1.z*xa.z + wa1.w*xa.w
                                + wb1.x*xb.x + wb1.y*xb.y + wb1.z*xb.z + wb1.w*xb.w;
                acc[r0] += hv0;
                acc[r1] += hv1;
                (&hq.x)[rp] = pkh(hv0, hv1);
            }
            hatg[(size_t)(b * N_ + n0 + nl) * 64 + le] = hq;
        }
    }

    // epilogue: t=0 partials (x 1/32), fp16, slab = [8 b][256 half2]
    __half2* pout = p1 + (size_t)(bg * HSLOT + slot) * (8 * 256);
    uint4 st;
    st.x = pkh(acc[0]*0.03125f, acc[1]*0.03125f);
    st.y = pkh(acc[2]*0.03125f, acc[3]*0.03125f);
    st.z = pkh(acc[4]*0.03125f, acc[5]*0.03125f);
    st.w = pkh(acc[6]*0.03125f, acc[7]*0.03125f);
    *(uint4*)(pout + wu * 256 + le * 4) = st;
}

// ---------------- caps_route: WAVE-independent routing pass ----------------
// R17: old route spent its time in per-block structure (LDS round-trip +
// __syncthreads + 8-way cross-wave serial reduce) at 2 blocks/CU -- ~30us
// for ~12us of L3 reads. New: unit = (b, 6 n) per WAVE. No LDS, no barriers,
// no cross-wave reduce: load 6 uint4 -> 2x 3-chain batched softmax -> acc ->
// store one 192-slab partial. ~56 VGPR; latency hidden by pure TLP.
// 192 % 8 == 0 so a block never straddles a b boundary.
__global__ __launch_bounds__(STH, 2) void caps_route(
    const uint4* __restrict__ hatg, const float* __restrict__ accb,
    float* __restrict__ p2)
{
    const int tid  = threadIdx.x;
    const int wu   = __builtin_amdgcn_readfirstlane(tid) >> 6;
    const int gw   = blockIdx.x * 8 + wu;    // global wave id, 0..12287
    const int b    = gw / NU;
    const int u    = gw % NU;                // 6-n unit
    const int lane = tid & 63;
    const int c    = lane & 31;
    const int h    = lane >> 5;
    const int le   = 2 * c + h;

    const float* ap = accb + (size_t)b * 512 + le * 8;
    const float4 a0 = *(const float4*)ap;
    const float4 a1 = *(const float4*)(ap + 4);

    const uint4* hb = hatg + (size_t)(b * N_ + u * 6) * 64 + le;

    uint4 v[6];
#pragma unroll
    for (int m = 0; m < 6; m++)
        v[m] = hb[(size_t)m * 64];

    float acc[8] = {0.f,0.f,0.f,0.f,0.f,0.f,0.f,0.f};
#pragma unroll
    for (int g = 0; g < 2; g++) {
        float lg[3], sm[3];
#pragma unroll
        for (int j = 0; j < 3; j++) {
            const uint4 vv = v[g * 3 + j];
            const float2 f0 = uph(vv.x);
            const float2 f1 = uph(vv.y);
            const float2 f2 = uph(vv.z);
            const float2 f3 = uph(vv.w);
            lg[j] = f0.x*a0.x + f0.y*a0.y + f1.x*a0.z + f1.y*a0.w
                  + f2.x*a1.x + f2.y*a1.y + f3.x*a1.z + f3.y*a1.w;
        }
#pragma unroll
        for (int j = 0; j < 3; j++) lg[j] += __shfl_xor(lg[j], 32, 64);  // i-halves
#pragma unroll
        for (int j = 0; j < 3; j++) { lg[j] = __expf(lg[j]); sm[j] = lg[j]; }
#pragma unroll
        for (int d = 16; d >= 1; d >>= 1)
#pragma unroll
            for (int j = 0; j < 3; j++) sm[j] += __shfl_xor(sm[j], d, 64);  // over c
#pragma unroll
        for (int j = 0; j < 3; j++) {
            const float sc = lg[j] * __builtin_amdgcn_rcpf(sm[j]);
            const uint4 vv = v[g * 3 + j];
            const float2 f0 = uph(vv.x);
            const float2 f1 = uph(vv.y);
            const float2 f2 = uph(vv.z);
            const float2 f3 = uph(vv.w);
            acc[0] += sc * f0.x; acc[1] += sc * f0.y;
            acc[2] += sc * f1.x; acc[3] += sc * f1.y;
            acc[4] += sc * f2.x; acc[5] += sc * f2.y;
            acc[6] += sc * f3.x; acc[7] += sc * f3.y;
        }
    }
    float* pb = p2 + ((size_t)b * NU + u) * 512 + le * 8;
    *(float4*)pb       = make_float4(acc[0], acc[1], acc[2], acc[3]);
    *(float4*)(pb + 4) = make_float4(acc[4], acc[5], acc[6], acc[7]);
}

// ---------------- caps_r1: reduce 1536 fp16 slot-slabs (t=0), squash -------
// p1 layout [bg(8)*HSLOT + slot][8 b][256 half2]
__global__ __launch_bounds__(512) void caps_r1(
    const __half2* __restrict__ p1, float* __restrict__ accb,
    float* __restrict__ out, int t)
{
    const int b   = blockIdx.x >> 2;     // 0..63
    const int q   = blockIdx.x & 3;
    const int tid = threadIdx.x;
    const int ep  = tid >> 3;            // 0..63: e-pair within q-range
    const int p   = tid & 7;             // 8-way slab split
    const int bg  = b >> 3, bl = b & 7;
    const __half2* base = p1 + (size_t)bg * HSLOT * 2048 + bl * 256 + (q * 64 + ep);
    float vx = 0.f, vy = 0.f;
#pragma unroll 8
    for (int ch = p; ch < HSLOT; ch += 8) {
        const float2 f = __half22float2(base[(size_t)ch * 2048]);
        vx += f.x; vy += f.y;
    }
    vx += __shfl_xor(vx, 1, 64);  vy += __shfl_xor(vy, 1, 64);
    vx += __shfl_xor(vx, 2, 64);  vy += __shfl_xor(vy, 2, 64);
    vx += __shfl_xor(vx, 4, 64);  vy += __shfl_xor(vy, 4, 64);
    float sq = vx * vx + vy * vy;
    sq += __shfl_xor(sq, 8, 64);
    sq += __shfl_xor(sq, 16, 64);
    sq += __shfl_xor(sq, 32, 64);
    const float scale = sq / (1.f + sq) * rsqrtf(sq + 1e-7f);
    if (p == 0) {
        const int oidx = b * 512 + q * 128 + ep * 2;
        const float ox = vx * scale, oy = vy * scale;
        if (t == 2) { out[oidx] = ox; out[oidx + 1] = oy; }
        else if (t == 0) { accb[oidx] = ox; accb[oidx + 1] = oy; }
        else { accb[oidx] += ox; accb[oidx + 1] += oy; }
    }
}

// ---------------- caps_r2: reduce route's 192 wave-slabs per b, squash -----
// R17: 256 blocks (b,q); 4-way slab split + shfl combine; i-reduce over
// tid bits 2..5 (e = q*128 + tid>>2, so e&15 = tid bits 2..5).
__global__ __launch_bounds__(512) void caps_r2(
    const float* __restrict__ p2, float* __restrict__ accb,
    float* __restrict__ out, int t)
{
    const int b   = blockIdx.x >> 2;
    const int q   = blockIdx.x & 3;
    const int tid = threadIdx.x;
    const int e   = q * 128 + (tid >> 2);
    const int p   = tid & 3;
    const float* base = p2 + (size_t)b * (NU * 512) + e;
    float v = 0.f;
#pragma unroll 8
    for (int s = p; s < NU; s += 4)
        v += base[(size_t)s * 512];
    v += __shfl_xor(v, 1, 64);
    v += __shfl_xor(v, 2, 64);
    float sq = v * v;
    sq += __shfl_xor(sq, 4, 64);
    sq += __shfl_xor(sq, 8, 64);
    sq += __shfl_xor(sq, 16, 64);
    sq += __shfl_xor(sq, 32, 64);
    const float scale = sq / (1.f + sq) * rsqrtf(sq + 1e-7f);
    const float ov = v * scale;
    if (p == 0) {
        const int oidx = b * 512 + e;
        if (t == 2) out[oidx] = ov;
        else        accb[oidx] += ov;
    }
}

// ---------------- fallback (R5 path, 16.9 MB ws) ---------------------------
__global__ __launch_bounds__(STH, 2) void caps_s_fb(
    const float* __restrict__ X, const float* __restrict__ W,
    const float* __restrict__ aout, float* __restrict__ partials, int t)
{
    __shared__ float wlds[FCH * 64 * 64];
    __shared__ float xlds[FCH * 16 * 8];
    const int bg = blockIdx.x & 3, slot = blockIdx.x >> 2;
    const int tid = threadIdx.x, w = tid >> 6, lane = tid & 63;
    const int c = lane & 31, h = lane >> 5, bl0 = w * 2, sw = c & 7;
    float areg[2][8] = {};
    if (t > 0) {
#pragma unroll
        for (int bq = 0; bq < 2; bq++) {
            const float* ap = aout + (size_t)(bg * 16 + bl0 + bq) * 512 + c * 16 + h * 8;
            const float4 a0 = *(const float4*)ap; const float4 a1 = *(const float4*)(ap + 4);
            areg[bq][0]=a0.x; areg[bq][1]=a0.y; areg[bq][2]=a0.z; areg[bq][3]=a0.w;
            areg[bq][4]=a1.x; areg[bq][5]=a1.y; areg[bq][6]=a1.z; areg[bq][7]=a1.w;
        }
    }
    float acc[2][8];
#pragma unroll
    for (int bq = 0; bq < 2; bq++)
#pragma unroll
        for (int r = 0; r < 8; r++) acc[bq][r] = 0.f;
    for (int cc = 0; cc < 3; cc++) {
        if (cc) __syncthreads();
        const int n0 = (slot + cc * FSLOT) * FCH;
        for (int G = tid; G < FCH * 1024; G += STH) {
            const int nl = G >> 10, f = (G >> 4) & 63, q = G & 15;
            const int wc = f >> 1, wh = f & 1;
            const float4 v = *(const float4*)(W + (size_t)(wc * N_ + n0 + nl) * 128 + wh * 64 + q * 4);
            *(float4*)(wlds + (nl * 64 + f) * 64 + (q ^ (wc & 7)) * 4) = v;
        }
        if (tid < FCH * 32) {
            const int nl = tid >> 5, bl = (tid >> 1) & 15, qx = tid & 1;
            const float4 v = *(const float4*)(X + (size_t)((bg * 16 + bl) * N_ + n0 + nl) * DI_ + qx * 4);
            *(float4*)(xlds + (nl * 16 + bl) * 8 + qx * 4) = v;
        }
        __syncthreads();
#pragma unroll
        for (int nl = 0; nl < FCH; nl++) {
            float4 xa[2], xb[2];
#pragma unroll
            for (int bq = 0; bq < 2; bq++) {
                const float* xp = xlds + (nl * 16 + bl0 + bq) * 8;
                xa[bq] = *(const float4*)xp; xb[bq] = *(const float4*)(xp + 4);
            }
            float hat[2][8];
            const float* frag = wlds + (nl * 64 + 2 * c + h) * 64;
#pragma unroll
            for (int r = 0; r < 8; r++) {
                const int pa = ((2 * r) ^ sw) * 4; const int pb = pa ^ 4;
                const float4 wa = *(const float4*)(frag + pa);
                const float4 wb = *(const float4*)(frag + pb);
#pragma unroll
                for (int bq = 0; bq < 2; bq++)
                    hat[bq][r] = wa.x*xa[bq].x + wa.y*xa[bq].y + wa.z*xa[bq].z + wa.w*xa[bq].w
                               + wb.x*xb[bq].x + wb.y*xb[bq].y + wb.z*xb[bq].z + wb.w*xb[bq].w;
            }
#pragma unroll
            for (int bq = 0; bq < 2; bq++) {
                float softc;
                if (t > 0) {
                    float lg = hat[bq][0]*areg[bq][0] + hat[bq][1]*areg[bq][1]
                             + hat[bq][2]*areg[bq][2] + hat[bq][3]*areg[bq][3]
                             + hat[bq][4]*areg[bq][4] + hat[bq][5]*areg[bq][5]
                             + hat[bq][6]*areg[bq][6] + hat[bq][7]*areg[bq][7];
                    lg += __shfl_xor(lg, 32, 64);
                    const float e = __expf(lg);
                    float s = e;
#pragma unroll
                    for (int m = 16; m >= 1; m >>= 1) s += __shfl_xor(s, m, 64);
                    softc = e / s;
                } else softc = 1.0f / 32.0f;
#pragma unroll
                for (int r = 0; r < 8; r++) acc[bq][r] += softc * hat[bq][r];
            }
        }
    }
    float* pout = partials + (size_t)(bg * FSLOT + slot) * (16 * 512);
#pragma unroll
    for (int bq = 0; bq < 2; bq++) {
        float* pb = pout + (bl0 + bq) * 512 + c * 16 + h * 8;
        *(float4*)pb       = make_float4(acc[bq][0], acc[bq][1], acc[bq][2], acc[bq][3]);
        *(float4*)(pb + 4) = make_float4(acc[bq][4], acc[bq][5], acc[bq][6], acc[bq][7]);
    }
}

__global__ __launch_bounds__(256) void caps_r1_fb(
    const float* __restrict__ partials, float* __restrict__ accb,
    float* __restrict__ out, int t)
{
    const int b   = blockIdx.x >> 2;
    const int q   = blockIdx.x & 3;
    const int tid = threadIdx.x;
    const int e   = q * 128 + (tid >> 1);
    const int p   = tid & 1;
    const int bg  = b >> 4, bl = b & 15;
    const float* base = partials + (size_t)bg * FSLOT * 8192 + (size_t)bl * 512 + e;
    float v = 0.f;
#pragma unroll 8
    for (int ch = p; ch < FSLOT; ch += 2)
        v += base[(size_t)ch * 8192];
    v += __shfl_xor(v, 1, 64);
    float sq = v * v;
#pragma unroll
    for (int m = 2; m <= 16; m <<= 1) sq += __shfl_xor(sq, m, 64);
    const float scale = sq / (1.f + sq) * rsqrtf(sq + 1e-7f);
    const float ov = v * scale;
    if (p == 0) {
        const int oidx = b * 512 + e;
        if (t == 2) out[oidx] = ov;
        else        accb[oidx] = (t == 0) ? ov : (accb[oidx] + ov);
    }
}

extern "C" void kernel_launch(void* const* d_in, const int* in_sizes, int n_in,
                              void* d_out, int out_size, void* d_ws, size_t ws_size,
                              hipStream_t stream) {
    const float* X = (const float*)d_in[0];   // [B,N,DI]
    const float* W = (const float*)d_in[1];   // [C,N,DC,DI]
    float* out = (float*)d_out;               // [B,C,DC]

    const size_t hat_b = (size_t)B_ * N_ * 512 * 2;        // 75,497,472 (fp16)
    const size_t p1_b  = (size_t)8 * HSLOT * 2048 * 4;     // 12,582,912 (fp16)
    const size_t p2_b  = (size_t)B_ * NU * 512 * 4;        // 25,165,824
    const size_t acc_b = (size_t)B_ * 512 * 4;             //    131,072

    if (ws_size >= hat_b + p1_b + p2_b + acc_b) {
        char* ws = (char*)d_ws;
        uint4*   hatg = (uint4*)ws;
        __half2* p1   = (__half2*)(ws + hat_b);
        float*   p2   = (float*)(ws + hat_b + p1_b);
        float*   accb = (float*)(ws + hat_b + p1_b + p2_b);
        caps_hat  <<<1536, STH, 0, stream>>>(X, W, hatg, p1);
        caps_r1   <<<256, 512, 0, stream>>>(p1, accb, out, 0);
        caps_route<<<(B_ * NU) / 8, STH, 0, stream>>>(hatg, accb, p2);
        caps_r2   <<<256, 512, 0, stream>>>(p2, accb, out, 1);
        caps_route<<<(B_ * NU) / 8, STH, 0, stream>>>(hatg, accb, p2);
        caps_r2   <<<256, 512, 0, stream>>>(p2, accb, out, 2);
    } else {
        float* partials = (float*)d_ws;
        float* accb = partials + (size_t)512 * 8192;
        for (int t = 0; t < 3; t++) {
            caps_s_fb<<<512, STH, 0, stream>>>(X, W, accb, partials, t);
            caps_r1_fb<<<256, 256, 0, stream>>>(partials, accb, out, t);
        }
    }
}

// Round 11
// 127.833 us; speedup vs baseline: 1.1349x; 1.1349x over previous
//
#include <hip/hip_runtime.h>
#include <hip/hip_bf16.h>
#include <hip/hip_fp16.h>

#define B_  64
#define C_  32
#define N_  1152
#define DI_ 8
#define DC_ 16
#define STH 512              // 8 waves

// main-path geometry
#define HCH 2                // n's per staged chunk (wlds 32KB)
#define HSLOT 192            // chunk-slots; slot handles chunks slot, +192, +384
#define NOCT 24              // route units of 48 n = one XCD's slot band

// fallback geometry (R5 path)
#define FCH 3
#define FSLOT 128

static __device__ __forceinline__ unsigned pkh(float a, float b) {
    __half2 t = __float22half2_rn(make_float2(a, b));
    return *reinterpret_cast<unsigned*>(&t);
}
static __device__ __forceinline__ float2 uph(unsigned u) {
    __half2 h; *reinterpret_cast<unsigned*>(&h) = u;
    return __half22float2(h);
}

// ---------------- caps_hat: hat = W@x once, fp16 out, + t=0 partials -------
// R18: R10's clean counters showed hat is LDS-pipe bound (~26us of ds_read/
// ds_write serialization; VALU 26%, HBM 27%, occ 44% -- nothing else close).
// bq=2: the same 8 frag ds_read_b128 now serve TWO b's -> LDS read traffic
// per b halves. NO wreg prefetch (that's what pushed R15 over the 64-VGPR
// budget the allocator enforces at LDS=32KB; peak live here ~58).
// Grid 768 = 4bg x 192 slots, XCD-banded: bid&7=xcd owns slots
// [24*xcd,24*xcd+24) so all 4 bg-blocks of a slot share one XCD's L2 for W.
__global__ __launch_bounds__(STH, 2) void caps_hat(
    const float* __restrict__ X, const float* __restrict__ W,
    uint4* __restrict__ hatg, __half2* __restrict__ p1)
{
    __shared__ float wlds[HCH * 64 * 64];    // [nl][f=2c+h][phys quad q^(c&7)]

    const int xcd  = blockIdx.x & 7;
    const int k    = blockIdx.x >> 3;        // 0..95
    const int bg   = k & 3;                  // 0..3 (16 b's each)
    const int slot = 24 * xcd + (k >> 2);    // 0..191, contiguous band per XCD

    const int tid  = threadIdx.x;
    const int lane = tid & 63;
    const int c    = lane & 31;
    const int h    = lane >> 5;
    const int le   = 2 * c + h;
    const int sw   = c & 7;
    const int wu   = __builtin_amdgcn_readfirstlane(tid) >> 6;  // uniform wave id
    const int bl0  = wu * 2;

    float acc[2][8];
#pragma unroll
    for (int bq = 0; bq < 2; bq++)
#pragma unroll
        for (int r = 0; r < 8; r++) acc[bq][r] = 0.f;

    for (int cc = 0; cc < 3; cc++) {
        if (cc) __syncthreads();
        const int n0 = (slot + cc * HSLOT) * HCH;

#pragma unroll
        for (int G = tid; G < HCH * 1024; G += STH) {   // 4 iters
            const int nl = G >> 10, f = (G >> 4) & 63, q = G & 15;
            const int wc = f >> 1, wh = f & 1;
            const float4 v = *(const float4*)(W + (size_t)(wc * N_ + n0 + nl) * 128 + wh * 64 + q * 4);
            *(float4*)(wlds + (nl * 64 + f) * 64 + (q ^ (wc & 7)) * 4) = v;
        }
        __syncthreads();

#pragma unroll
        for (int nl = 0; nl < HCH; nl++) {
            float4 xa[2], xb[2];
#pragma unroll
            for (int bq = 0; bq < 2; bq++) {
                const float* xp = X + ((size_t)(bg * 16 + bl0 + bq) * N_ + n0 + nl) * DI_;
                xa[bq] = *(const float4*)xp;
                xb[bq] = *(const float4*)(xp + 4);
            }
            uint4 hq[2];
            const float* frag = wlds + (nl * 64 + le) * 64;
#pragma unroll
            for (int rp = 0; rp < 4; rp++) {
                const int r0 = 2 * rp, r1 = r0 + 1;
                const int pa0 = ((2 * r0) ^ sw) * 4;
                const int pb0 = pa0 ^ 4;
                const int pa1 = ((2 * r1) ^ sw) * 4;
                const int pb1 = pa1 ^ 4;
                const float4 wa0 = *(const float4*)(frag + pa0);
                const float4 wb0 = *(const float4*)(frag + pb0);
                const float4 wa1 = *(const float4*)(frag + pa1);
                const float4 wb1 = *(const float4*)(frag + pb1);
#pragma unroll
                for (int bq = 0; bq < 2; bq++) {
                    const float hv0 = wa0.x*xa[bq].x + wa0.y*xa[bq].y + wa0.z*xa[bq].z + wa0.w*xa[bq].w
                                    + wb0.x*xb[bq].x + wb0.y*xb[bq].y + wb0.z*xb[bq].z + wb0.w*xb[bq].w;
                    const float hv1 = wa1.x*xa[bq].x + wa1.y*xa[bq].y + wa1.z*xa[bq].z + wa1.w*xa[bq].w
                                    + wb1.x*xb[bq].x + wb1.y*xb[bq].y + wb1.z*xb[bq].z + wb1.w*xb[bq].w;
                    acc[bq][r0] += hv0;
                    acc[bq][r1] += hv1;
                    (&hq[bq].x)[rp] = pkh(hv0, hv1);
                }
            }
#pragma unroll
            for (int bq = 0; bq < 2; bq++) {
                const int b = bg * 16 + bl0 + bq;
                hatg[(size_t)(b * N_ + n0 + nl) * 64 + le] = hq[bq];
            }
        }
    }

    // epilogue: t=0 partials (x 1/32), fp16, slab = [16 b][256 half2]
    __half2* pout = p1 + (size_t)(bg * HSLOT + slot) * (16 * 256);
#pragma unroll
    for (int bq = 0; bq < 2; bq++) {
        uint4 st;
        st.x = pkh(acc[bq][0]*0.03125f, acc[bq][1]*0.03125f);
        st.y = pkh(acc[bq][2]*0.03125f, acc[bq][3]*0.03125f);
        st.z = pkh(acc[bq][4]*0.03125f, acc[bq][5]*0.03125f);
        st.w = pkh(acc[bq][6]*0.03125f, acc[bq][7]*0.03125f);
        *(uint4*)(pout + (bl0 + bq) * 256 + le * 4) = st;
    }
}

// ---------------- caps_route: one routing pass over materialized fp16 hat --
// R9's verified version (129.7us config): unit u = the 48-n band one XCD
// wrote (u%8 == bid&7 -> same-L2 hat reads); 3-chain batched softmax fits
// the 64-VGPR regime; 8-wave block + LDS reduce.
__global__ __launch_bounds__(STH, 2) void caps_route(
    const uint4* __restrict__ hatg, const float* __restrict__ accb,
    float* __restrict__ p2)
{
    __shared__ float red[8 * 512];
    const int xcd  = blockIdx.x & 7;
    const int rest = blockIdx.x >> 3;        // 0..191
    const int ug   = rest % 3;
    const int b    = rest / 3;               // 0..63
    const int u    = 8 * ug + xcd;           // 0..23, u%8 == xcd
    const int tid  = threadIdx.x;
    const int w    = tid >> 6;
    const int lane = tid & 63;
    const int c    = lane & 31;
    const int h    = lane >> 5;
    const int le   = 2 * c + h;

    const float* ap = accb + (size_t)b * 512 + le * 8;
    const float4 a0 = *(const float4*)ap;
    const float4 a1 = *(const float4*)(ap + 4);

    const uint4* hb = hatg + (size_t)(b * N_ + u * 48) * 64 + le;

    uint4 v[6];
#pragma unroll
    for (int m = 0; m < 6; m++)
        v[m] = hb[(size_t)(w + 8 * m) * 64];

    float acc[8] = {0.f,0.f,0.f,0.f,0.f,0.f,0.f,0.f};
#pragma unroll
    for (int g = 0; g < 2; g++) {
        float lg[3], sm[3];
#pragma unroll
        for (int j = 0; j < 3; j++) {
            const uint4 vv = v[g * 3 + j];
            const float2 f0 = uph(vv.x);
            const float2 f1 = uph(vv.y);
            const float2 f2 = uph(vv.z);
            const float2 f3 = uph(vv.w);
            lg[j] = f0.x*a0.x + f0.y*a0.y + f1.x*a0.z + f1.y*a0.w
                  + f2.x*a1.x + f2.y*a1.y + f3.x*a1.z + f3.y*a1.w;
        }
#pragma unroll
        for (int j = 0; j < 3; j++) lg[j] += __shfl_xor(lg[j], 32, 64);  // i-halves
#pragma unroll
        for (int j = 0; j < 3; j++) { lg[j] = __expf(lg[j]); sm[j] = lg[j]; }
#pragma unroll
        for (int d = 16; d >= 1; d >>= 1)
#pragma unroll
            for (int j = 0; j < 3; j++) sm[j] += __shfl_xor(sm[j], d, 64);  // over c
#pragma unroll
        for (int j = 0; j < 3; j++) {
            const float sc = lg[j] * __builtin_amdgcn_rcpf(sm[j]);
            const uint4 vv = v[g * 3 + j];
            const float2 f0 = uph(vv.x);
            const float2 f1 = uph(vv.y);
            const float2 f2 = uph(vv.z);
            const float2 f3 = uph(vv.w);
            acc[0] += sc * f0.x; acc[1] += sc * f0.y;
            acc[2] += sc * f1.x; acc[3] += sc * f1.y;
            acc[4] += sc * f2.x; acc[5] += sc * f2.y;
            acc[6] += sc * f3.x; acc[7] += sc * f3.y;
        }
    }
    // block reduce over 8 waves
    *(float4*)(red + w * 512 + le * 8)     = make_float4(acc[0], acc[1], acc[2], acc[3]);
    *(float4*)(red + w * 512 + le * 8 + 4) = make_float4(acc[4], acc[5], acc[6], acc[7]);
    __syncthreads();
    float vs = 0.f;
#pragma unroll
    for (int s = 0; s < 8; s++) vs += red[s * 512 + tid];
    p2[(size_t)(b * NOCT + u) * 512 + tid] = vs;
}

// ---------------- caps_r1: reduce 768 fp16 slot-slabs (t=0), squash --------
// p1 layout [bg(4)*HSLOT + slot][16 b][256 half2]
__global__ __launch_bounds__(512) void caps_r1(
    const __half2* __restrict__ p1, float* __restrict__ accb,
    float* __restrict__ out, int t)
{
    const int b   = blockIdx.x >> 2;     // 0..63
    const int q   = blockIdx.x & 3;
    const int tid = threadIdx.x;
    const int ep  = tid >> 3;            // 0..63: e-pair within q-range
    const int p   = tid & 7;             // 8-way slab split
    const int bg  = b >> 4, bl = b & 15;
    const __half2* base = p1 + (size_t)bg * HSLOT * 4096 + bl * 256 + (q * 64 + ep);
    float vx = 0.f, vy = 0.f;
#pragma unroll 8
    for (int ch = p; ch < HSLOT; ch += 8) {
        const float2 f = __half22float2(base[(size_t)ch * 4096]);
        vx += f.x; vy += f.y;
    }
    vx += __shfl_xor(vx, 1, 64);  vy += __shfl_xor(vy, 1, 64);
    vx += __shfl_xor(vx, 2, 64);  vy += __shfl_xor(vy, 2, 64);
    vx += __shfl_xor(vx, 4, 64);  vy += __shfl_xor(vy, 4, 64);
    float sq = vx * vx + vy * vy;
    sq += __shfl_xor(sq, 8, 64);
    sq += __shfl_xor(sq, 16, 64);
    sq += __shfl_xor(sq, 32, 64);
    const float scale = sq / (1.f + sq) * rsqrtf(sq + 1e-7f);
    if (p == 0) {
        const int oidx = b * 512 + q * 128 + ep * 2;
        const float ox = vx * scale, oy = vy * scale;
        if (t == 2) { out[oidx] = ox; out[oidx + 1] = oy; }
        else if (t == 0) { accb[oidx] = ox; accb[oidx + 1] = oy; }
        else { accb[oidx] += ox; accb[oidx + 1] += oy; }
    }
}

// ---------------- caps_r2: reduce caps_route's 24 unit-slabs per b ---------
__global__ __launch_bounds__(512) void caps_r2(
    const float* __restrict__ p2, float* __restrict__ accb,
    float* __restrict__ out, int t)
{
    const int b = blockIdx.x;
    const int e = threadIdx.x;               // [c=e>>4][i=e&15]
    const float* base = p2 + (size_t)b * (NOCT * 512) + e;
    float v = 0.f;
#pragma unroll
    for (int s = 0; s < NOCT; s++) v += base[s * 512];
    float sq = v * v;
#pragma unroll
    for (int m = 1; m <= 8; m <<= 1) sq += __shfl_xor(sq, m, 64);  // sum over i
    const float scale = sq / (1.f + sq) * rsqrtf(sq + 1e-7f);
    const float ov = v * scale;
    const int oidx = b * 512 + e;
    if (t == 2) out[oidx] = ov;
    else        accb[oidx] += ov;
}

// ---------------- fallback (R5 path, 16.9 MB ws) ---------------------------
__global__ __launch_bounds__(STH, 2) void caps_s_fb(
    const float* __restrict__ X, const float* __restrict__ W,
    const float* __restrict__ aout, float* __restrict__ partials, int t)
{
    __shared__ float wlds[FCH * 64 * 64];
    __shared__ float xlds[FCH * 16 * 8];
    const int bg = blockIdx.x & 3, slot = blockIdx.x >> 2;
    const int tid = threadIdx.x, w = tid >> 6, lane = tid & 63;
    const int c = lane & 31, h = lane >> 5, bl0 = w * 2, sw = c & 7;
    float areg[2][8] = {};
    if (t > 0) {
#pragma unroll
        for (int bq = 0; bq < 2; bq++) {
            const float* ap = aout + (size_t)(bg * 16 + bl0 + bq) * 512 + c * 16 + h * 8;
            const float4 a0 = *(const float4*)ap; const float4 a1 = *(const float4*)(ap + 4);
            areg[bq][0]=a0.x; areg[bq][1]=a0.y; areg[bq][2]=a0.z; areg[bq][3]=a0.w;
            areg[bq][4]=a1.x; areg[bq][5]=a1.y; areg[bq][6]=a1.z; areg[bq][7]=a1.w;
        }
    }
    float acc[2][8];
#pragma unroll
    for (int bq = 0; bq < 2; bq++)
#pragma unroll
        for (int r = 0; r < 8; r++) acc[bq][r] = 0.f;
    for (int cc = 0; cc < 3; cc++) {
        if (cc) __syncthreads();
        const int n0 = (slot + cc * FSLOT) * FCH;
        for (int G = tid; G < FCH * 1024; G += STH) {
            const int nl = G >> 10, f = (G >> 4) & 63, q = G & 15;
            const int wc = f >> 1, wh = f & 1;
            const float4 v = *(const float4*)(W + (size_t)(wc * N_ + n0 + nl) * 128 + wh * 64 + q * 4);
            *(float4*)(wlds + (nl * 64 + f) * 64 + (q ^ (wc & 7)) * 4) = v;
        }
        if (tid < FCH * 32) {
            const int nl = tid >> 5, bl = (tid >> 1) & 15, qx = tid & 1;
            const float4 v = *(const float4*)(X + (size_t)((bg * 16 + bl) * N_ + n0 + nl) * DI_ + qx * 4);
            *(float4*)(xlds + (nl * 16 + bl) * 8 + qx * 4) = v;
        }
        __syncthreads();
#pragma unroll
        for (int nl = 0; nl < FCH; nl++) {
            float4 xa[2], xb[2];
#pragma unroll
            for (int bq = 0; bq < 2; bq++) {
                const float* xp = xlds + (nl * 16 + bl0 + bq) * 8;
                xa[bq] = *(const float4*)xp; xb[bq] = *(const float4*)(xp + 4);
            }
            float hat[2][8];
            const float* frag = wlds + (nl * 64 + 2 * c + h) * 64;
#pragma unroll
            for (int r = 0; r < 8; r++) {
                const int pa = ((2 * r) ^ sw) * 4; const int pb = pa ^ 4;
                const float4 wa = *(const float4*)(frag + pa);
                const float4 wb = *(const float4*)(frag + pb);
#pragma unroll
                for (int bq = 0; bq < 2; bq++)
                    hat[bq][r] = wa.x*xa[bq].x + wa.y*xa[bq].y + wa.z*xa[bq].z + wa.w*xa[bq].w
                               + wb.x*xb[bq].x + wb.y*xb[bq].y + wb.z*xb[bq].z + wb.w*xb[bq].w;
            }
#pragma unroll
            for (int bq = 0; bq < 2; bq++) {
                float softc;
                if (t > 0) {
                    float lg = hat[bq][0]*areg[bq][0] + hat[bq][1]*areg[bq][1]
                             + hat[bq][2]*areg[bq][2] + hat[bq][3]*areg[bq][3]
                             + hat[bq][4]*areg[bq][4] + hat[bq][5]*areg[bq][5]
                             + hat[bq][6]*areg[bq][6] + hat[bq][7]*areg[bq][7];
                    lg += __shfl_xor(lg, 32, 64);
                    const float e = __expf(lg);
                    float s = e;
#pragma unroll
                    for (int m = 16; m >= 1; m >>= 1) s += __shfl_xor(s, m, 64);
                    softc = e / s;
                } else softc = 1.0f / 32.0f;
#pragma unroll
                for (int r = 0; r < 8; r++) acc[bq][r] += softc * hat[bq][r];
            }
        }
    }
    float* pout = partials + (size_t)(bg * FSLOT + slot) * (16 * 512);
#pragma unroll
    for (int bq = 0; bq < 2; bq++) {
        float* pb = pout + (bl0 + bq) * 512 + c * 16 + h * 8;
        *(float4*)pb       = make_float4(acc[bq][0], acc[bq][1], acc[bq][2], acc[bq][3]);
        *(float4*)(pb + 4) = make_float4(acc[bq][4], acc[bq][5], acc[bq][6], acc[bq][7]);
    }
}

__global__ __launch_bounds__(256) void caps_r1_fb(
    const float* __restrict__ partials, float* __restrict__ accb,
    float* __restrict__ out, int t)
{
    const int b   = blockIdx.x >> 2;
    const int q   = blockIdx.x & 3;
    const int tid = threadIdx.x;
    const int e   = q * 128 + (tid >> 1);
    const int p   = tid & 1;
    const int bg  = b >> 4, bl = b & 15;
    const float* base = partials + (size_t)bg * FSLOT * 8192 + (size_t)bl * 512 + e;
    float v = 0.f;
#pragma unroll 8
    for (int ch = p; ch < FSLOT; ch += 2)
        v += base[(size_t)ch * 8192];
    v += __shfl_xor(v, 1, 64);
    float sq = v * v;
#pragma unroll
    for (int m = 2; m <= 16; m <<= 1) sq += __shfl_xor(sq, m, 64);
    const float scale = sq / (1.f + sq) * rsqrtf(sq + 1e-7f);
    const float ov = v * scale;
    if (p == 0) {
        const int oidx = b * 512 + e;
        if (t == 2) out[oidx] = ov;
        else        accb[oidx] = (t == 0) ? ov : (accb[oidx] + ov);
    }
}

extern "C" void kernel_launch(void* const* d_in, const int* in_sizes, int n_in,
                              void* d_out, int out_size, void* d_ws, size_t ws_size,
                              hipStream_t stream) {
    const float* X = (const float*)d_in[0];   // [B,N,DI]
    const float* W = (const float*)d_in[1];   // [C,N,DC,DI]
    float* out = (float*)d_out;               // [B,C,DC]

    const size_t hat_b = (size_t)B_ * N_ * 512 * 2;        // 75,497,472 (fp16)
    const size_t p1_b  = (size_t)4 * HSLOT * 4096 * 4;     // 12,582,912 (fp16)
    const size_t p2_b  = (size_t)B_ * NOCT * 512 * 4;      //  3,145,728
    const size_t acc_b = (size_t)B_ * 512 * 4;             //    131,072

    if (ws_size >= hat_b + p1_b + p2_b + acc_b) {
        char* ws = (char*)d_ws;
        uint4*   hatg = (uint4*)ws;
        __half2* p1   = (__half2*)(ws + hat_b);
        float*   p2   = (float*)(ws + hat_b + p1_b);
        float*   accb = (float*)(ws + hat_b + p1_b + p2_b);
        caps_hat  <<<768, STH, 0, stream>>>(X, W, hatg, p1);
        caps_r1   <<<256, 512, 0, stream>>>(p1, accb, out, 0);
        caps_route<<<B_ * NOCT, STH, 0, stream>>>(hatg, accb, p2);
        caps_r2   <<<64, 512, 0, stream>>>(p2, accb, out, 1);
        caps_route<<<B_ * NOCT, STH, 0, stream>>>(hatg, accb, p2);
        caps_r2   <<<64, 512, 0, stream>>>(p2, accb, out, 2);
    } else {
        float* partials = (float*)d_ws;
        float* accb = partials + (size_t)512 * 8192;
        for (int t = 0; t < 3; t++) {
            caps_s_fb<<<512, STH, 0, stream>>>(X, W, accb, partials, t);
            caps_r1_fb<<<256, 256, 0, stream>>>(partials, accb, out, t);
        }
    }
}